// Round 1
// baseline (1076.673 us; speedup 1.0000x reference)
//
#include <hip/hip_runtime.h>
#include <cstdint>
#include <cstddef>

namespace {

constexpr int kH  = 1024;
constexpr int kB  = 64;
constexpr int kN  = 32;
constexpr int kT  = 400;
constexpr int kV  = 32000;
constexpr int kM  = kN * kB;   // 2048
constexpr int k3H = 3 * kH;    // 3072

typedef _Float16 f16;
typedef _Float16 f16x4 __attribute__((ext_vector_type(4)));
typedef _Float16 f16x8 __attribute__((ext_vector_type(8)));
typedef float    f32x4v __attribute__((ext_vector_type(4)));

__device__ __forceinline__ void gload_lds16(const void* g, void* l) {
  __builtin_amdgcn_global_load_lds((__attribute__((address_space(1))) void*)g,
                                   (__attribute__((address_space(3))) void*)l,
                                   16, 0, 0);
}

// ---------------- elementwise helpers ----------------

__global__ void cvt_f16_kernel(const float* __restrict__ src, f16* __restrict__ dst, int n4) {
  int i = blockIdx.x * blockDim.x + threadIdx.x;
  const int stride = gridDim.x * blockDim.x;
  for (; i < n4; i += stride) {
    float4 v = reinterpret_cast<const float4*>(src)[i];
    f16x4 o = { (f16)v.x, (f16)v.y, (f16)v.z, (f16)v.w };
    reinterpret_cast<f16x4*>(dst)[i] = o;
  }
}

__global__ void gather_x_kernel(const int* __restrict__ seq, const float* __restrict__ emb,
                                f16* __restrict__ xh) {
  const int m = blockIdx.x;               // 0..2047 = n*64+b
  const int tok = seq[m];
  float4 v = reinterpret_cast<const float4*>(emb + (size_t)tok * kH)[threadIdx.x];
  f16x4 o = { (f16)v.x, (f16)v.y, (f16)v.z, (f16)v.w };
  reinterpret_cast<f16x4*>(xh + (size_t)m * kH)[threadIdx.x] = o;
}

__global__ void init_h_kernel(const float* __restrict__ lh, float* __restrict__ h0,
                              f16* __restrict__ hh0) {
  const int i = blockIdx.x * blockDim.x + threadIdx.x;   // 16384 float4s
  float4 v = reinterpret_cast<const float4*>(lh)[i];
  reinterpret_cast<float4*>(h0)[i] = v;
  f16x4 o = { (f16)v.x, (f16)v.y, (f16)v.z, (f16)v.w };
  reinterpret_cast<f16x4*>(hh0)[i] = o;
}

// ---------------- main GEMM: C = A * Bt^T (+bias)(+tanh) ----------------
// A: [M][K] f16, Bt: [N][K] f16 (weights are (out,in) row-major = ready-transposed)
// 128x128 tile, BK=64, 4 waves, wave = 64x64 via 4x4 mfma_f32_16x16x32_f16.

template <bool TANH, typename OUT_T>
__global__ __launch_bounds__(256)
void gemm_bt_kernel(const f16* __restrict__ A, const f16* __restrict__ Bt,
                    const float* __restrict__ bias, OUT_T* __restrict__ C,
                    int M, int N, int K) {
  __shared__ __align__(16) f16 As[128 * 64];
  __shared__ __align__(16) f16 Bs[128 * 64];
  const int tid  = threadIdx.x;
  const int wave = tid >> 6;
  const int lane = tid & 63;
  const int m0 = blockIdx.x * 128;
  const int n0 = blockIdx.y * 128;
  const int wm = (wave >> 1) * 64;
  const int wn = (wave & 1) * 64;
  const int rsub = lane >> 3;          // staging: row within 8-row chunk
  const int coff = (lane & 7) * 8;     // staging: f16 col offset (16B per lane)
  f32x4v acc[4][4] = {};
  const int nk = K >> 6;
  for (int kc = 0; kc < nk; ++kc) {
    const f16* Ag = A + (size_t)m0 * K + kc * 64;
    const f16* Bg = Bt + (size_t)n0 * K + kc * 64;
    for (int c = wave; c < 16; c += 4) {        // 16 chunks of 1KB each for A and B
      const int row = c * 8 + rsub;
      gload_lds16(Ag + (size_t)row * K + coff, &As[c * 512]);
      gload_lds16(Bg + (size_t)row * K + coff, &Bs[c * 512]);
    }
    __syncthreads();
    #pragma unroll
    for (int kk = 0; kk < 2; ++kk) {
      const int ko = kk * 32 + (lane >> 4) * 8;
      f16x8 af[4], bfr[4];
      #pragma unroll
      for (int i = 0; i < 4; ++i) {
        af[i]  = *reinterpret_cast<const f16x8*>(&As[(wm + i * 16 + (lane & 15)) * 64 + ko]);
        bfr[i] = *reinterpret_cast<const f16x8*>(&Bs[(wn + i * 16 + (lane & 15)) * 64 + ko]);
      }
      #pragma unroll
      for (int mi = 0; mi < 4; ++mi)
        #pragma unroll
        for (int ni = 0; ni < 4; ++ni)
          acc[mi][ni] = __builtin_amdgcn_mfma_f32_16x16x32_f16(af[mi], bfr[ni], acc[mi][ni], 0, 0, 0);
    }
    __syncthreads();
  }
  // epilogue: D row = (lane>>4)*4+r, col = lane&15
  const int rb = (lane >> 4) * 4;
  const int cb = lane & 15;
  #pragma unroll
  for (int mi = 0; mi < 4; ++mi) {
    #pragma unroll
    for (int ni = 0; ni < 4; ++ni) {
      const int col = n0 + wn + ni * 16 + cb;
      const float bv = bias[col];
      #pragma unroll
      for (int r = 0; r < 4; ++r) {
        const int row = m0 + wm + mi * 16 + rb + r;
        float v = acc[mi][ni][r] + bv;
        if (TANH) v = tanhf(v);
        C[(size_t)row * N + col] = (OUT_T)v;
      }
    }
  }
}

// ---------------- fused GRU step ----------------
// gh = h @ W_hh^T for 3 gate sections x 32 cols per block (grid=32), then gates fused.
// Block: 384 threads = 6 waves = (3 sections) x (2 halves of 16 cols). M=64 (batch).

__global__ __launch_bounds__(384)
void gru_step_kernel(const f16* __restrict__ hh, const float* __restrict__ h,
                     const f16* __restrict__ Whh, const float* __restrict__ bhh,
                     const float* __restrict__ gi, int step,
                     float* __restrict__ hout, f16* __restrict__ hhout,
                     f16* __restrict__ cath, float* __restrict__ hiddenOut) {
  __shared__ __align__(16) f16 As[2][64 * 64];    // h tile (double-buffered)
  __shared__ __align__(16) f16 Bs[2][96 * 64];    // W_hh rows: 3 sections x 32
  __shared__ float ghs[3][64][32];
  const int tid  = threadIdx.x;
  const int wave = tid >> 6;
  const int lane = tid & 63;
  const int g = blockIdx.x;            // col group 0..31
  const int s  = wave >> 1;            // gate section 0..2
  const int hn = wave & 1;             // 16-col half
  const int rsub = lane >> 3;
  const int coff = (lane & 7) * 8;
  f32x4v acc[4] = {};

  auto stage = [&](int kc, int buf) {
    for (int c = wave; c < 20; c += 6) {          // 8 A-chunks + 12 B-chunks (1KB each)
      if (c < 8) {
        const int row = c * 8 + rsub;
        gload_lds16(hh + (size_t)row * kH + kc * 64 + coff, &As[buf][c * 512]);
      } else {
        const int rl = (c - 8) * 8 + rsub;        // 0..95
        const int ss = rl >> 5;
        const int jj = rl & 31;
        const int j = ss * kH + g * 32 + jj;
        gload_lds16(Whh + (size_t)j * kH + kc * 64 + coff, &Bs[buf][(c - 8) * 512]);
      }
    }
  };

  stage(0, 0);
  __syncthreads();
  int cur = 0;
  for (int kc = 0; kc < 16; ++kc) {
    if (kc < 15) stage(kc + 1, cur ^ 1);          // async prefetch overlaps MFMA
    #pragma unroll
    for (int kk = 0; kk < 2; ++kk) {
      const int ko = kk * 32 + (lane >> 4) * 8;
      f16x8 bfr = *reinterpret_cast<const f16x8*>(
          &Bs[cur][(s * 32 + hn * 16 + (lane & 15)) * 64 + ko]);
      #pragma unroll
      for (int mi = 0; mi < 4; ++mi) {
        f16x8 af = *reinterpret_cast<const f16x8*>(
            &As[cur][(mi * 16 + (lane & 15)) * 64 + ko]);
        acc[mi] = __builtin_amdgcn_mfma_f32_16x16x32_f16(af, bfr, acc[mi], 0, 0, 0);
      }
    }
    __syncthreads();
    cur ^= 1;
  }
  #pragma unroll
  for (int mi = 0; mi < 4; ++mi)
    #pragma unroll
    for (int r = 0; r < 4; ++r)
      ghs[s][mi * 16 + (lane >> 4) * 4 + r][hn * 16 + (lane & 15)] = acc[mi][r];
  __syncthreads();

  for (int t = tid; t < 2048; t += 384) {
    const int b  = t >> 5;
    const int jj = t & 31;
    const int j  = g * 32 + jj;
    const size_t m = (size_t)step * kB + b;
    const float gr = ghs[0][b][jj] + bhh[j];
    const float gz = ghs[1][b][jj] + bhh[kH + j];
    const float gn = ghs[2][b][jj] + bhh[2 * kH + j];
    const float ir  = gi[m * k3H + j];
    const float iz  = gi[m * k3H + kH + j];
    const float inn = gi[m * k3H + 2 * kH + j];
    const float r  = 1.0f / (1.0f + expf(-(ir + gr)));
    const float z  = 1.0f / (1.0f + expf(-(iz + gz)));
    const float nn = tanhf(inn + r * gn);
    const float ho = h[b * kH + j];
    const float hv = (1.0f - z) * nn + z * ho;
    hout[b * kH + j] = hv;
    hhout[b * kH + j] = (f16)hv;
    cath[m * k3H + j] = (f16)hv;                  // rnn_out section of concat buffer
    if (hiddenOut) hiddenOut[b * kH + j] = hv;
  }
}

// ---------------- attention (softmax over t is independent of n) ----------------

__global__ void attn_prep_kernel(const float* __restrict__ attn_W, const float* __restrict__ attn_b,
                                 const float* __restrict__ v, float* __restrict__ u2,
                                 float* __restrict__ biasS) {
  const int h = blockIdx.x;        // 0..1023 -> u2[h]; 1024 -> bias scalar
  const int lane = threadIdx.x;    // 64
  float sum = 0.0f;
  if (h < kH) {
    for (int k = lane; k < kH; k += 64)
      sum += attn_W[(size_t)k * (2 * kH) + kH + h] * v[k];
  } else {
    for (int k = lane; k < kH; k += 64)
      sum += attn_b[k] * v[k];
  }
  #pragma unroll
  for (int o = 32; o > 0; o >>= 1) sum += __shfl_xor(sum, o);
  if (lane == 0) {
    if (h < kH) u2[h] = sum; else biasS[0] = sum;
  }
}

__global__ void attn_scores_kernel(const float* __restrict__ enc0, const float* __restrict__ enc1,
                                   const float* __restrict__ u2, const float* __restrict__ biasS,
                                   float* __restrict__ c) {
  const int wid  = blockIdx.x * 4 + (threadIdx.x >> 6);  // one wave per (e,t,b)
  const int lane = threadIdx.x & 63;
  const int e   = wid / (kT * kB);
  const int rem = wid % (kT * kB);
  const int t = rem / kB;
  const int b = rem % kB;
  const float* row = (e ? enc1 : enc0) + ((size_t)t * kB + b) * kH;
  float sum = 0.0f;
  #pragma unroll
  for (int i = 0; i < 4; ++i) {
    float4 ev = *reinterpret_cast<const float4*>(&row[i * 256 + lane * 4]);
    float4 uv = *reinterpret_cast<const float4*>(&u2[i * 256 + lane * 4]);
    sum += ev.x * uv.x + ev.y * uv.y + ev.z * uv.z + ev.w * uv.w;
  }
  #pragma unroll
  for (int o = 32; o > 0; o >>= 1) sum += __shfl_xor(sum, o);
  if (lane == 0) c[((size_t)e * kB + b) * kT + t] = sum + biasS[0];
}

__global__ void attn_softmax_kernel(const float* __restrict__ c, float* __restrict__ wsm,
                                    float* __restrict__ uw, float* __restrict__ bw) {
  const int eb = blockIdx.x;       // 0..127
  const int e = eb >> 6, b = eb & 63;
  __shared__ float row[kT];
  __shared__ float red[8];
  const float* cr = c + (size_t)eb * kT;
  const int tid = threadIdx.x;     // 256
  float lmax = -1e30f;
  for (int t = tid; t < kT; t += 256) { float v = cr[t]; row[t] = v; lmax = fmaxf(lmax, v); }
  #pragma unroll
  for (int o = 32; o > 0; o >>= 1) lmax = fmaxf(lmax, __shfl_xor(lmax, o));
  if ((tid & 63) == 0) red[tid >> 6] = lmax;
  __syncthreads();
  const float m = fmaxf(fmaxf(red[0], red[1]), fmaxf(red[2], red[3]));
  float lsum = 0.0f;
  for (int t = tid; t < kT; t += 256) { float ev = expf(row[t] - m); row[t] = ev; lsum += ev; }
  #pragma unroll
  for (int o = 32; o > 0; o >>= 1) lsum += __shfl_xor(lsum, o);
  if ((tid & 63) == 0) red[4 + (tid >> 6)] = lsum;
  __syncthreads();
  const float inv = 1.0f / (red[4] + red[5] + red[6] + red[7]);
  for (int t = tid; t < kT; t += 256) row[t] *= inv;
  __syncthreads();
  float* wrow = wsm + (size_t)eb * kT;
  for (int t = tid; t < kT; t += 256) wrow[t] = row[t];
  float* outp = (e ? bw : uw) + (size_t)b * kN * kT;   // w is identical for every n
  for (int i = tid; i < kN * kT; i += 256) outp[i] = row[i % kT];
}

__global__ void attn_ctx_kernel(const float* __restrict__ enc0, const float* __restrict__ enc1,
                                const float* __restrict__ wsm, f16* __restrict__ cath) {
  const int bid = blockIdx.x;          // e(2) x b(64) x hc(4)
  const int hc = bid & 3;
  const int b  = (bid >> 2) & 63;
  const int e  = bid >> 8;
  const float* enc = e ? enc1 : enc0;
  __shared__ float w[kT];
  const int tid = threadIdx.x;         // 256
  const float* wrow = wsm + ((size_t)e * kB + b) * kT;
  for (int t = tid; t < kT; t += 256) w[t] = wrow[t];
  __syncthreads();
  const int hcol = hc * 256 + tid;
  float acc = 0.0f;
  #pragma unroll 4
  for (int t = 0; t < kT; ++t)
    acc += w[t] * enc[((size_t)t * kB + b) * kH + hcol];
  const f16 v = (f16)acc;
  #pragma unroll
  for (int n = 0; n < kN; ++n)         // ctx is independent of n -> replicate
    cath[((size_t)(n * kB + b)) * k3H + kH + e * kH + hcol] = v;
}

}  // namespace

// ---------------- launch ----------------

extern "C" void kernel_launch(void* const* d_in, const int* in_sizes, int n_in,
                              void* d_out, int out_size, void* d_ws, size_t ws_size,
                              hipStream_t stream) {
  (void)in_sizes; (void)n_in; (void)out_size; (void)ws_size;
  const int*   seq    = (const int*)d_in[0];
  const float* lh     = (const float*)d_in[1];
  const float* enc0   = (const float*)d_in[2];
  const float* enc1   = (const float*)d_in[3];
  const float* emb    = (const float*)d_in[4];
  const float* W_ih   = (const float*)d_in[5];
  const float* W_hh   = (const float*)d_in[6];
  const float* b_ih   = (const float*)d_in[7];
  const float* b_hh   = (const float*)d_in[8];
  const float* attn_W = (const float*)d_in[9];
  const float* attn_b = (const float*)d_in[10];
  const float* attn_v = (const float*)d_in[11];
  const float* cW     = (const float*)d_in[12];
  const float* cb     = (const float*)d_in[13];
  const float* oW     = (const float*)d_in[14];
  const float* ob     = (const float*)d_in[15];
  float* out = (float*)d_out;

  // workspace layout (all 256B-aligned by construction)
  char* ws = (char*)d_ws;
  constexpr size_t oWih = 0;                         // 3072x1024 f16
  constexpr size_t oWhh = oWih + 6291456;
  constexpr size_t oCW  = oWhh + 6291456;
  constexpr size_t oOW  = oCW + 6291456;             // 32000x1024 f16
  constexpr size_t oX   = oOW + 65536000;            // 2048x1024 f16
  constexpr size_t oGI  = oX + 4194304;              // 2048x3072 f32
  constexpr size_t oH0  = oGI + 25165824;            // 64x1024 f32
  constexpr size_t oH1  = oH0 + 262144;
  constexpr size_t oHH0 = oH1 + 262144;              // 64x1024 f16
  constexpr size_t oHH1 = oHH0 + 131072;
  constexpr size_t oCAT = oHH1 + 131072;             // 2048x3072 f16
  constexpr size_t oH2  = oCAT + 12582912;           // 2048x1024 f16
  constexpr size_t oU2  = oH2 + 4194304;             // 1024 f32
  constexpr size_t oBS  = oU2 + 4096;                // 1 f32
  constexpr size_t oC   = oBS + 256;                 // 2x64x400 f32
  constexpr size_t oWSM = oC + 204800;               // 2x64x400 f32

  f16*   Wih_h = (f16*)(ws + oWih);
  f16*   Whh_h = (f16*)(ws + oWhh);
  f16*   cW_h  = (f16*)(ws + oCW);
  f16*   oW_h  = (f16*)(ws + oOW);
  f16*   X_h   = (f16*)(ws + oX);
  float* GI    = (float*)(ws + oGI);
  float* H0    = (float*)(ws + oH0);
  float* H1    = (float*)(ws + oH1);
  f16*   HH0   = (f16*)(ws + oHH0);
  f16*   HH1   = (f16*)(ws + oHH1);
  f16*   CAT   = (f16*)(ws + oCAT);
  f16*   H2    = (f16*)(ws + oH2);
  float* U2    = (float*)(ws + oU2);
  float* BS    = (float*)(ws + oBS);
  float* Cb    = (float*)(ws + oC);
  float* WSM   = (float*)(ws + oWSM);

  constexpr size_t oHidden = (size_t)kM * kV;        // 65,536,000
  constexpr size_t oUW = oHidden + (size_t)kB * kH;  // 65,601,536
  constexpr size_t oBW = oUW + (size_t)kB * kN * kT; // 66,420,736

  // weight converts f32 -> f16
  cvt_f16_kernel<<<1024, 256, 0, stream>>>(W_ih, Wih_h, k3H * kH / 4);
  cvt_f16_kernel<<<1024, 256, 0, stream>>>(W_hh, Whh_h, k3H * kH / 4);
  cvt_f16_kernel<<<1024, 256, 0, stream>>>(cW,   cW_h,  kH * k3H / 4);
  cvt_f16_kernel<<<2048, 256, 0, stream>>>(oW,   oW_h,  kV * kH / 4);
  gather_x_kernel<<<kM, 256, 0, stream>>>(seq, emb, X_h);
  init_h_kernel<<<64, 256, 0, stream>>>(lh, H0, HH0);

  // gi = x @ W_ih^T + b_ih  (batched over all steps)
  gemm_bt_kernel<false, float><<<dim3(16, 24), 256, 0, stream>>>(X_h, Wih_h, b_ih, GI, kM, k3H, kH);

  // GRU recurrence
  for (int n = 0; n < kN; ++n) {
    const float* hin  = (n & 1) ? H1 : H0;
    float*       hoo  = (n & 1) ? H0 : H1;
    const f16*   hhin = (n & 1) ? HH1 : HH0;
    f16*         hhoo = (n & 1) ? HH0 : HH1;
    gru_step_kernel<<<32, 384, 0, stream>>>(hhin, hin, Whh_h, b_hh, GI, n, hoo, hhoo, CAT,
                                            (n == kN - 1) ? (out + oHidden) : nullptr);
  }

  // attention (n-independent): scores -> softmax (writes uw/bw replicated) -> ctx
  attn_prep_kernel<<<1025, 64, 0, stream>>>(attn_W, attn_b, attn_v, U2, BS);
  attn_scores_kernel<<<2 * kT * kB / 4, 256, 0, stream>>>(enc0, enc1, U2, BS, Cb);
  attn_softmax_kernel<<<128, 256, 0, stream>>>(Cb, WSM, out + oUW, out + oBW);
  attn_ctx_kernel<<<512, 256, 0, stream>>>(enc0, enc1, WSM, CAT);

  // h = tanh(cat @ concat_W^T + concat_b)   (f16 out for final GEMM)
  gemm_bt_kernel<true, f16><<<dim3(16, 8), 256, 0, stream>>>(CAT, cW_h, cb, H2, kM, kH, k3H);
  // output = h @ out_W^T + out_b
  gemm_bt_kernel<false, float><<<dim3(16, 250), 256, 0, stream>>>(H2, oW_h, ob, out, kM, kV, kH);
}

// Round 2
// 909.913 us; speedup vs baseline: 1.1833x; 1.1833x over previous
//
#include <hip/hip_runtime.h>
#include <cstdint>
#include <cstddef>

namespace {

constexpr int kH  = 1024;
constexpr int kB  = 64;
constexpr int kN  = 32;
constexpr int kT  = 400;
constexpr int kV  = 32000;
constexpr int kM  = kN * kB;   // 2048
constexpr int k3H = 3 * kH;    // 3072

typedef _Float16 f16;
typedef _Float16 f16x4 __attribute__((ext_vector_type(4)));
typedef _Float16 f16x8 __attribute__((ext_vector_type(8)));
typedef float    f32x4v __attribute__((ext_vector_type(4)));

__device__ __forceinline__ void gload_lds16(const void* g, void* l) {
  __builtin_amdgcn_global_load_lds((__attribute__((address_space(1))) void*)g,
                                   (__attribute__((address_space(3))) void*)l,
                                   16, 0, 0);
}

// ---------------- elementwise helpers ----------------

__global__ void cvt_f16_kernel(const float* __restrict__ src, f16* __restrict__ dst, int n4) {
  int i = blockIdx.x * blockDim.x + threadIdx.x;
  const int stride = gridDim.x * blockDim.x;
  for (; i < n4; i += stride) {
    float4 v = reinterpret_cast<const float4*>(src)[i];
    f16x4 o = { (f16)v.x, (f16)v.y, (f16)v.z, (f16)v.w };
    reinterpret_cast<f16x4*>(dst)[i] = o;
  }
}

__global__ void gather_x_kernel(const int* __restrict__ seq, const float* __restrict__ emb,
                                f16* __restrict__ xh) {
  const int m = blockIdx.x;               // 0..2047 = n*64+b
  const int tok = seq[m];
  float4 v = reinterpret_cast<const float4*>(emb + (size_t)tok * kH)[threadIdx.x];
  f16x4 o = { (f16)v.x, (f16)v.y, (f16)v.z, (f16)v.w };
  reinterpret_cast<f16x4*>(xh + (size_t)m * kH)[threadIdx.x] = o;
}

__global__ void init_h_kernel(const float* __restrict__ lh, float* __restrict__ h0,
                              f16* __restrict__ hh0) {
  const int i = blockIdx.x * blockDim.x + threadIdx.x;   // 16384 float4s
  float4 v = reinterpret_cast<const float4*>(lh)[i];
  reinterpret_cast<float4*>(h0)[i] = v;
  f16x4 o = { (f16)v.x, (f16)v.y, (f16)v.z, (f16)v.w };
  reinterpret_cast<f16x4*>(hh0)[i] = o;
}

// ---------------- main GEMM: C = A * Bt^T (+bias)(+tanh) ----------------
// A: [M][K] f16, Bt: [N][K] f16 (weights are (out,in) row-major = ready-transposed)
// 128x128 tile, BK=64, 4 waves, wave = 64x64 via 4x4 mfma_f32_16x16x32_f16.

template <bool TANH, typename OUT_T>
__global__ __launch_bounds__(256)
void gemm_bt_kernel(const f16* __restrict__ A, const f16* __restrict__ Bt,
                    const float* __restrict__ bias, OUT_T* __restrict__ C,
                    int M, int N, int K) {
  __shared__ __align__(16) f16 As[128 * 64];
  __shared__ __align__(16) f16 Bs[128 * 64];
  const int tid  = threadIdx.x;
  const int wave = tid >> 6;
  const int lane = tid & 63;
  const int m0 = blockIdx.x * 128;
  const int n0 = blockIdx.y * 128;
  const int wm = (wave >> 1) * 64;
  const int wn = (wave & 1) * 64;
  const int rsub = lane >> 3;          // staging: row within 8-row chunk
  const int coff = (lane & 7) * 8;     // staging: f16 col offset (16B per lane)
  f32x4v acc[4][4] = {};
  const int nk = K >> 6;
  for (int kc = 0; kc < nk; ++kc) {
    const f16* Ag = A + (size_t)m0 * K + kc * 64;
    const f16* Bg = Bt + (size_t)n0 * K + kc * 64;
    for (int c = wave; c < 16; c += 4) {        // 16 chunks of 1KB each for A and B
      const int row = c * 8 + rsub;
      gload_lds16(Ag + (size_t)row * K + coff, &As[c * 512]);
      gload_lds16(Bg + (size_t)row * K + coff, &Bs[c * 512]);
    }
    __syncthreads();
    #pragma unroll
    for (int kk = 0; kk < 2; ++kk) {
      const int ko = kk * 32 + (lane >> 4) * 8;
      f16x8 af[4], bfr[4];
      #pragma unroll
      for (int i = 0; i < 4; ++i) {
        af[i]  = *reinterpret_cast<const f16x8*>(&As[(wm + i * 16 + (lane & 15)) * 64 + ko]);
        bfr[i] = *reinterpret_cast<const f16x8*>(&Bs[(wn + i * 16 + (lane & 15)) * 64 + ko]);
      }
      #pragma unroll
      for (int mi = 0; mi < 4; ++mi)
        #pragma unroll
        for (int ni = 0; ni < 4; ++ni)
          acc[mi][ni] = __builtin_amdgcn_mfma_f32_16x16x32_f16(af[mi], bfr[ni], acc[mi][ni], 0, 0, 0);
    }
    __syncthreads();
  }
  // epilogue: D row = (lane>>4)*4+r, col = lane&15
  const int rb = (lane >> 4) * 4;
  const int cb = lane & 15;
  #pragma unroll
  for (int mi = 0; mi < 4; ++mi) {
    #pragma unroll
    for (int ni = 0; ni < 4; ++ni) {
      const int col = n0 + wn + ni * 16 + cb;
      const float bv = bias[col];
      #pragma unroll
      for (int r = 0; r < 4; ++r) {
        const int row = m0 + wm + mi * 16 + rb + r;
        float v = acc[mi][ni][r] + bv;
        if (TANH) v = tanhf(v);
        C[(size_t)row * N + col] = (OUT_T)v;
      }
    }
  }
}

// ---------------- persistent GRU ----------------
// 64 blocks x 256 threads, 1 block/CU. Block owns output cols j0..j0+15 across
// all 3 gate sections. W_hh fragments live in REGISTERS for all 32 steps
// (wave w owns K-slice w*256..w*256+256: 3 sections x 8 k-slices = 24 f16x8).
// Per step: h fragments loaded direct global->reg (no LDS, no intra-step
// barriers), 96 MFMA/wave, K-split partials reduced via padded LDS, gate math
// fused, then a device-scope release/acquire barrier between steps.

__global__ __launch_bounds__(256, 1)
void gru_persist_kernel(const f16* __restrict__ Whh, const float* __restrict__ bhh,
                        const float* __restrict__ gi,
                        float* __restrict__ Ha, float* __restrict__ Hb,
                        f16* __restrict__ HHa, f16* __restrict__ HHb,
                        f16* __restrict__ cath, float* __restrict__ hiddenOut,
                        unsigned int* __restrict__ ctr) {
  __shared__ float ghp[4][64][49];     // [wave][m][48 cols, padded] partials
  const int tid  = threadIdx.x;
  const int wave = tid >> 6;
  const int lane = tid & 63;
  const int ln   = lane & 15;
  const int khi  = lane >> 4;
  const int j0   = blockIdx.x * 16;
  const int kw   = wave * 256;         // this wave's K-slice

  // B fragments: persistent in registers across all steps (96 VGPR)
  f16x8 bfr[3][8];
  #pragma unroll
  for (int s = 0; s < 3; ++s)
    #pragma unroll
    for (int ks = 0; ks < 8; ++ks)
      bfr[s][ks] = *reinterpret_cast<const f16x8*>(
          &Whh[(size_t)(s * kH + j0 + ln) * kH + kw + ks * 32 + khi * 8]);

  for (int step = 0; step < kN; ++step) {
    const f16*   hh  = (step & 1) ? HHb : HHa;
    const float* hf  = (step & 1) ? Hb  : Ha;
    float*       hfo = (step & 1) ? Ha  : Hb;
    f16*         hho = (step & 1) ? HHa : HHb;

    // A fragments: direct global->reg, all 32 loads in flight at once
    f16x8 af[8][4];
    #pragma unroll
    for (int ks = 0; ks < 8; ++ks)
      #pragma unroll
      for (int mi = 0; mi < 4; ++mi)
        af[ks][mi] = *reinterpret_cast<const f16x8*>(
            &hh[(size_t)(mi * 16 + ln) * kH + kw + ks * 32 + khi * 8]);

    f32x4v acc[4][3] = {};
    #pragma unroll
    for (int ks = 0; ks < 8; ++ks)
      #pragma unroll
      for (int mi = 0; mi < 4; ++mi)
        #pragma unroll
        for (int s = 0; s < 3; ++s)
          acc[mi][s] = __builtin_amdgcn_mfma_f32_16x16x32_f16(af[ks][mi], bfr[s][ks], acc[mi][s], 0, 0, 0);

    // K-split partials -> LDS (padded pitch 49: conflict-free)
    #pragma unroll
    for (int mi = 0; mi < 4; ++mi)
      #pragma unroll
      for (int s = 0; s < 3; ++s)
        #pragma unroll
        for (int r = 0; r < 4; ++r)
          ghp[wave][mi * 16 + khi * 4 + r][s * 16 + ln] = acc[mi][s][r];
    __syncthreads();

    // gate fusion: 64 m x 16 j = 1024 elements, 4 per thread
    #pragma unroll
    for (int t4 = 0; t4 < 4; ++t4) {
      const int t  = t4 * 256 + tid;
      const int m  = t >> 4;
      const int jj = t & 15;
      const int j  = j0 + jj;
      const float gr = ghp[0][m][jj]      + ghp[1][m][jj]      + ghp[2][m][jj]      + ghp[3][m][jj]      + bhh[j];
      const float gz = ghp[0][m][16 + jj] + ghp[1][m][16 + jj] + ghp[2][m][16 + jj] + ghp[3][m][16 + jj] + bhh[kH + j];
      const float gn = ghp[0][m][32 + jj] + ghp[1][m][32 + jj] + ghp[2][m][32 + jj] + ghp[3][m][32 + jj] + bhh[2 * kH + j];
      const size_t mm = (size_t)step * kB + m;
      const float ir  = gi[mm * k3H + j];
      const float iz  = gi[mm * k3H + kH + j];
      const float inn = gi[mm * k3H + 2 * kH + j];
      const float r  = 1.0f / (1.0f + expf(-(ir + gr)));
      const float z  = 1.0f / (1.0f + expf(-(iz + gz)));
      const float nn = tanhf(inn + r * gn);
      const float ho = hf[m * kH + j];
      const float hv = (1.0f - z) * nn + z * ho;
      hfo[m * kH + j] = hv;
      hho[m * kH + j] = (f16)hv;
      cath[mm * (size_t)k3H + j] = (f16)hv;
      if (step == kN - 1) hiddenOut[m * kH + j] = hv;
    }
    __syncthreads();   // LDS reuse next step; also drains this block's stores

    if (step < kN - 1) {
      if (tid == 0) {
        // release: wbL2 before count becomes visible -> h_new globally visible
        __hip_atomic_fetch_add(&ctr[step], 1u, __ATOMIC_RELEASE, __HIP_MEMORY_SCOPE_AGENT);
        // acquire spin: invalidates this CU's L1 + XCD L2 on success
        while (__hip_atomic_load(&ctr[step], __ATOMIC_ACQUIRE, __HIP_MEMORY_SCOPE_AGENT) < 64u)
          __builtin_amdgcn_s_sleep(2);
      }
      __syncthreads();
    }
  }
}

// ---------------- attention (softmax over t is independent of n) ----------------

__global__ void attn_prep_kernel(const float* __restrict__ attn_W, const float* __restrict__ attn_b,
                                 const float* __restrict__ v, float* __restrict__ u2,
                                 float* __restrict__ biasS) {
  const int h = blockIdx.x;        // 0..1023 -> u2[h]; 1024 -> bias scalar
  const int lane = threadIdx.x;    // 64
  float sum = 0.0f;
  if (h < kH) {
    for (int k = lane; k < kH; k += 64)
      sum += attn_W[(size_t)k * (2 * kH) + kH + h] * v[k];
  } else {
    for (int k = lane; k < kH; k += 64)
      sum += attn_b[k] * v[k];
  }
  #pragma unroll
  for (int o = 32; o > 0; o >>= 1) sum += __shfl_xor(sum, o);
  if (lane == 0) {
    if (h < kH) u2[h] = sum; else biasS[0] = sum;
  }
}

__global__ void attn_scores_kernel(const float* __restrict__ enc0, const float* __restrict__ enc1,
                                   const float* __restrict__ u2, const float* __restrict__ biasS,
                                   float* __restrict__ c) {
  const int wid  = blockIdx.x * 4 + (threadIdx.x >> 6);  // one wave per (e,t,b)
  const int lane = threadIdx.x & 63;
  const int e   = wid / (kT * kB);
  const int rem = wid % (kT * kB);
  const int t = rem / kB;
  const int b = rem % kB;
  const float* row = (e ? enc1 : enc0) + ((size_t)t * kB + b) * kH;
  float sum = 0.0f;
  #pragma unroll
  for (int i = 0; i < 4; ++i) {
    float4 ev = *reinterpret_cast<const float4*>(&row[i * 256 + lane * 4]);
    float4 uv = *reinterpret_cast<const float4*>(&u2[i * 256 + lane * 4]);
    sum += ev.x * uv.x + ev.y * uv.y + ev.z * uv.z + ev.w * uv.w;
  }
  #pragma unroll
  for (int o = 32; o > 0; o >>= 1) sum += __shfl_xor(sum, o);
  if (lane == 0) c[((size_t)e * kB + b) * kT + t] = sum + biasS[0];
}

__global__ void attn_softmax_kernel(const float* __restrict__ c, float* __restrict__ wsm,
                                    float* __restrict__ uw, float* __restrict__ bw) {
  const int eb = blockIdx.x;       // 0..127
  const int e = eb >> 6, b = eb & 63;
  __shared__ float row[kT];
  __shared__ float red[8];
  const float* cr = c + (size_t)eb * kT;
  const int tid = threadIdx.x;     // 256
  float lmax = -1e30f;
  for (int t = tid; t < kT; t += 256) { float v = cr[t]; row[t] = v; lmax = fmaxf(lmax, v); }
  #pragma unroll
  for (int o = 32; o > 0; o >>= 1) lmax = fmaxf(lmax, __shfl_xor(lmax, o));
  if ((tid & 63) == 0) red[tid >> 6] = lmax;
  __syncthreads();
  const float m = fmaxf(fmaxf(red[0], red[1]), fmaxf(red[2], red[3]));
  float lsum = 0.0f;
  for (int t = tid; t < kT; t += 256) { float ev = expf(row[t] - m); row[t] = ev; lsum += ev; }
  #pragma unroll
  for (int o = 32; o > 0; o >>= 1) lsum += __shfl_xor(lsum, o);
  if ((tid & 63) == 0) red[4 + (tid >> 6)] = lsum;
  __syncthreads();
  const float inv = 1.0f / (red[4] + red[5] + red[6] + red[7]);
  for (int t = tid; t < kT; t += 256) row[t] *= inv;
  __syncthreads();
  float* wrow = wsm + (size_t)eb * kT;
  for (int t = tid; t < kT; t += 256) wrow[t] = row[t];
  float* outp = (e ? bw : uw) + (size_t)b * kN * kT;   // w is identical for every n
  for (int i = tid; i < kN * kT; i += 256) outp[i] = row[i % kT];
}

__global__ void attn_ctx_kernel(const float* __restrict__ enc0, const float* __restrict__ enc1,
                                const float* __restrict__ wsm, f16* __restrict__ cath) {
  const int bid = blockIdx.x;          // e(2) x b(64) x hc(4)
  const int hc = bid & 3;
  const int b  = (bid >> 2) & 63;
  const int e  = bid >> 8;
  const float* enc = e ? enc1 : enc0;
  __shared__ float w[kT];
  const int tid = threadIdx.x;         // 256
  const float* wrow = wsm + ((size_t)e * kB + b) * kT;
  for (int t = tid; t < kT; t += 256) w[t] = wrow[t];
  __syncthreads();
  const int hcol = hc * 256 + tid;
  float acc = 0.0f;
  #pragma unroll 4
  for (int t = 0; t < kT; ++t)
    acc += w[t] * enc[((size_t)t * kB + b) * kH + hcol];
  const f16 v = (f16)acc;
  #pragma unroll
  for (int n = 0; n < kN; ++n)         // ctx is independent of n -> replicate
    cath[((size_t)(n * kB + b)) * k3H + kH + e * kH + hcol] = v;
}

}  // namespace

// ---------------- launch ----------------

extern "C" void kernel_launch(void* const* d_in, const int* in_sizes, int n_in,
                              void* d_out, int out_size, void* d_ws, size_t ws_size,
                              hipStream_t stream) {
  (void)in_sizes; (void)n_in; (void)out_size; (void)ws_size;
  const int*   seq    = (const int*)d_in[0];
  const float* lh     = (const float*)d_in[1];
  const float* enc0   = (const float*)d_in[2];
  const float* enc1   = (const float*)d_in[3];
  const float* emb    = (const float*)d_in[4];
  const float* W_ih   = (const float*)d_in[5];
  const float* W_hh   = (const float*)d_in[6];
  const float* b_ih   = (const float*)d_in[7];
  const float* b_hh   = (const float*)d_in[8];
  const float* attn_W = (const float*)d_in[9];
  const float* attn_b = (const float*)d_in[10];
  const float* attn_v = (const float*)d_in[11];
  const float* cW     = (const float*)d_in[12];
  const float* cb     = (const float*)d_in[13];
  const float* oW     = (const float*)d_in[14];
  const float* ob     = (const float*)d_in[15];
  float* out = (float*)d_out;

  // workspace layout (all 256B-aligned by construction)
  char* ws = (char*)d_ws;
  constexpr size_t oWih = 0;                         // 3072x1024 f16
  constexpr size_t oWhh = oWih + 6291456;
  constexpr size_t oCW  = oWhh + 6291456;
  constexpr size_t oOW  = oCW + 6291456;             // 32000x1024 f16
  constexpr size_t oX   = oOW + 65536000;            // 2048x1024 f16
  constexpr size_t oGI  = oX + 4194304;              // 2048x3072 f32
  constexpr size_t oH0  = oGI + 25165824;            // 64x1024 f32
  constexpr size_t oH1  = oH0 + 262144;
  constexpr size_t oHH0 = oH1 + 262144;              // 64x1024 f16
  constexpr size_t oHH1 = oHH0 + 131072;
  constexpr size_t oCAT = oHH1 + 131072;             // 2048x3072 f16
  constexpr size_t oH2  = oCAT + 12582912;           // 2048x1024 f16
  constexpr size_t oU2  = oH2 + 4194304;             // 1024 f32
  constexpr size_t oBS  = oU2 + 4096;                // 1 f32
  constexpr size_t oC   = oBS + 256;                 // 2x64x400 f32
  constexpr size_t oWSM = oC + 204800;               // 2x64x400 f32
  constexpr size_t oCTR = oWSM + 204800;             // 64 u32 barrier counters

  f16*   Wih_h = (f16*)(ws + oWih);
  f16*   Whh_h = (f16*)(ws + oWhh);
  f16*   cW_h  = (f16*)(ws + oCW);
  f16*   oW_h  = (f16*)(ws + oOW);
  f16*   X_h   = (f16*)(ws + oX);
  float* GI    = (float*)(ws + oGI);
  float* H0    = (float*)(ws + oH0);
  float* H1    = (float*)(ws + oH1);
  f16*   HH0   = (f16*)(ws + oHH0);
  f16*   HH1   = (f16*)(ws + oHH1);
  f16*   CAT   = (f16*)(ws + oCAT);
  f16*   H2    = (f16*)(ws + oH2);
  float* U2    = (float*)(ws + oU2);
  float* BS    = (float*)(ws + oBS);
  float* Cb    = (float*)(ws + oC);
  float* WSM   = (float*)(ws + oWSM);
  unsigned int* CTR = (unsigned int*)(ws + oCTR);

  constexpr size_t oHidden = (size_t)kM * kV;        // 65,536,000
  constexpr size_t oUW = oHidden + (size_t)kB * kH;  // 65,601,536
  constexpr size_t oBW = oUW + (size_t)kB * kN * kT; // 66,420,736

  // weight converts f32 -> f16
  cvt_f16_kernel<<<1024, 256, 0, stream>>>(W_ih, Wih_h, k3H * kH / 4);
  cvt_f16_kernel<<<1024, 256, 0, stream>>>(W_hh, Whh_h, k3H * kH / 4);
  cvt_f16_kernel<<<1024, 256, 0, stream>>>(cW,   cW_h,  kH * k3H / 4);
  cvt_f16_kernel<<<2048, 256, 0, stream>>>(oW,   oW_h,  kV * kH / 4);
  gather_x_kernel<<<kM, 256, 0, stream>>>(seq, emb, X_h);
  init_h_kernel<<<64, 256, 0, stream>>>(lh, H0, HH0);
  hipMemsetAsync(CTR, 0, 64 * sizeof(unsigned int), stream);

  // gi = x @ W_ih^T + b_ih  (batched over all steps)
  gemm_bt_kernel<false, float><<<dim3(16, 24), 256, 0, stream>>>(X_h, Wih_h, b_ih, GI, kM, k3H, kH);

  // GRU recurrence: one persistent kernel, device barrier between steps
  gru_persist_kernel<<<64, 256, 0, stream>>>(Whh_h, b_hh, GI, H0, H1, HH0, HH1, CAT,
                                             out + oHidden, CTR);

  // attention (n-independent): scores -> softmax (writes uw/bw replicated) -> ctx
  attn_prep_kernel<<<1025, 64, 0, stream>>>(attn_W, attn_b, attn_v, U2, BS);
  attn_scores_kernel<<<2 * kT * kB / 4, 256, 0, stream>>>(enc0, enc1, U2, BS, Cb);
  attn_softmax_kernel<<<128, 256, 0, stream>>>(Cb, WSM, out + oUW, out + oBW);
  attn_ctx_kernel<<<512, 256, 0, stream>>>(enc0, enc1, WSM, CAT);

  // h = tanh(cat @ concat_W^T + concat_b)   (f16 out for final GEMM)
  gemm_bt_kernel<true, f16><<<dim3(16, 8), 256, 0, stream>>>(CAT, cW_h, cb, H2, kM, kH, k3H);
  // output = h @ out_W^T + out_b
  gemm_bt_kernel<false, float><<<dim3(16, 250), 256, 0, stream>>>(H2, oW_h, ob, out, kM, kV, kH);
}

// Round 3
// 768.191 us; speedup vs baseline: 1.4016x; 1.1845x over previous
//
#include <hip/hip_runtime.h>
#include <cstdint>
#include <cstddef>

namespace {

constexpr int kH  = 1024;
constexpr int kB  = 64;
constexpr int kN  = 32;
constexpr int kT  = 400;
constexpr int kV  = 32000;
constexpr int kM  = kN * kB;   // 2048
constexpr int k3H = 3 * kH;    // 3072

typedef _Float16 f16;
typedef _Float16 f16x4 __attribute__((ext_vector_type(4)));
typedef _Float16 f16x8 __attribute__((ext_vector_type(8)));
typedef float    f32x4v __attribute__((ext_vector_type(4)));

__device__ __forceinline__ void gload_lds16(const void* g, void* l) {
  __builtin_amdgcn_global_load_lds((__attribute__((address_space(1))) void*)g,
                                   (__attribute__((address_space(3))) void*)l,
                                   16, 0, 0);
}

__device__ __forceinline__ uint32_t pack_f16x2(f16 lo, f16 hi) {
  union { f16 h[2]; uint32_t u; } c;
  c.h[0] = lo; c.h[1] = hi;
  return c.u;
}

// ---------------- elementwise helpers ----------------

__global__ void cvt_f16_kernel(const float* __restrict__ src, f16* __restrict__ dst, int n4) {
  int i = blockIdx.x * blockDim.x + threadIdx.x;
  const int stride = gridDim.x * blockDim.x;
  for (; i < n4; i += stride) {
    float4 v = reinterpret_cast<const float4*>(src)[i];
    f16x4 o = { (f16)v.x, (f16)v.y, (f16)v.z, (f16)v.w };
    reinterpret_cast<f16x4*>(dst)[i] = o;
  }
}

__global__ void gather_x_kernel(const int* __restrict__ seq, const float* __restrict__ emb,
                                f16* __restrict__ xh) {
  const int m = blockIdx.x;               // 0..2047 = n*64+b
  const int tok = seq[m];
  float4 v = reinterpret_cast<const float4*>(emb + (size_t)tok * kH)[threadIdx.x];
  f16x4 o = { (f16)v.x, (f16)v.y, (f16)v.z, (f16)v.w };
  reinterpret_cast<f16x4*>(xh + (size_t)m * kH)[threadIdx.x] = o;
}

__global__ void init_h_kernel(const float* __restrict__ lh, f16* __restrict__ hh0) {
  const int i = blockIdx.x * blockDim.x + threadIdx.x;   // 16384 float4s
  float4 v = reinterpret_cast<const float4*>(lh)[i];
  f16x4 o = { (f16)v.x, (f16)v.y, (f16)v.z, (f16)v.w };
  reinterpret_cast<f16x4*>(hh0)[i] = o;
}

// ---------------- main GEMM: C = A * Bt^T (+bias)(+tanh) ----------------
// A: [M][K] f16, Bt: [N][K] f16 (weights are (out,in) row-major = ready-transposed)
// 128x128 tile, BK=64, 4 waves, wave = 64x64 via 4x4 mfma_f32_16x16x32_f16.

template <bool TANH, typename OUT_T>
__global__ __launch_bounds__(256)
void gemm_bt_kernel(const f16* __restrict__ A, const f16* __restrict__ Bt,
                    const float* __restrict__ bias, OUT_T* __restrict__ C,
                    int M, int N, int K) {
  __shared__ __align__(16) f16 As[128 * 64];
  __shared__ __align__(16) f16 Bs[128 * 64];
  const int tid  = threadIdx.x;
  const int wave = tid >> 6;
  const int lane = tid & 63;
  const int m0 = blockIdx.x * 128;
  const int n0 = blockIdx.y * 128;
  const int wm = (wave >> 1) * 64;
  const int wn = (wave & 1) * 64;
  const int rsub = lane >> 3;          // staging: row within 8-row chunk
  const int coff = (lane & 7) * 8;     // staging: f16 col offset (16B per lane)
  f32x4v acc[4][4] = {};
  const int nk = K >> 6;
  for (int kc = 0; kc < nk; ++kc) {
    const f16* Ag = A + (size_t)m0 * K + kc * 64;
    const f16* Bg = Bt + (size_t)n0 * K + kc * 64;
    for (int c = wave; c < 16; c += 4) {        // 16 chunks of 1KB each for A and B
      const int row = c * 8 + rsub;
      gload_lds16(Ag + (size_t)row * K + coff, &As[c * 512]);
      gload_lds16(Bg + (size_t)row * K + coff, &Bs[c * 512]);
    }
    __syncthreads();
    #pragma unroll
    for (int kk = 0; kk < 2; ++kk) {
      const int ko = kk * 32 + (lane >> 4) * 8;
      f16x8 af[4], bfr[4];
      #pragma unroll
      for (int i = 0; i < 4; ++i) {
        af[i]  = *reinterpret_cast<const f16x8*>(&As[(wm + i * 16 + (lane & 15)) * 64 + ko]);
        bfr[i] = *reinterpret_cast<const f16x8*>(&Bs[(wn + i * 16 + (lane & 15)) * 64 + ko]);
      }
      #pragma unroll
      for (int mi = 0; mi < 4; ++mi)
        #pragma unroll
        for (int ni = 0; ni < 4; ++ni)
          acc[mi][ni] = __builtin_amdgcn_mfma_f32_16x16x32_f16(af[mi], bfr[ni], acc[mi][ni], 0, 0, 0);
    }
    __syncthreads();
  }
  // epilogue: D row = (lane>>4)*4+r, col = lane&15
  const int rb = (lane >> 4) * 4;
  const int cb = lane & 15;
  #pragma unroll
  for (int mi = 0; mi < 4; ++mi) {
    #pragma unroll
    for (int ni = 0; ni < 4; ++ni) {
      const int col = n0 + wn + ni * 16 + cb;
      const float bv = bias[col];
      #pragma unroll
      for (int r = 0; r < 4; ++r) {
        const int row = m0 + wm + mi * 16 + rb + r;
        float v = acc[mi][ni][r] + bv;
        if (TANH) v = tanhf(v);
        C[(size_t)row * N + col] = (OUT_T)v;
      }
    }
  }
}

// ---------------- persistent GRU ----------------
// 64 blocks x 256 threads, 1 block/CU. Block owns output cols j0..j0+15.
// W_hh fragments persistent in registers (wave w owns K-slice w*256).
// Own-column h kept in f32 registers across steps (hreg).
// Cross-block h exchange: packed-f16 RELAXED agent atomic stores (sc1
// write-through to coherence point -> no wbl2 needed anywhere), counter add
// RELAXED, poll ACQUIRE (inv guarantees fresh reads; proven deadlock-free).

__global__ __launch_bounds__(256, 1)
void gru_persist_kernel(const f16* __restrict__ Whh, const float* __restrict__ bhh,
                        const float* __restrict__ gi, const float* __restrict__ lh,
                        f16* __restrict__ HHa, f16* __restrict__ HHb,
                        f16* __restrict__ cath, float* __restrict__ hiddenOut,
                        unsigned int* __restrict__ ctr) {
  __shared__ float ghp[4][64][49];     // [wave][m][48 cols, padded] partials
  const int tid  = threadIdx.x;
  const int wave = tid >> 6;
  const int lane = tid & 63;
  const int ln   = lane & 15;
  const int khi  = lane >> 4;
  const int j0   = blockIdx.x * 16;
  const int kw   = wave * 256;         // this wave's K-slice
  const int q    = tid & 7;            // fusion: col pair index
  const int mB   = tid >> 3;           // fusion: row base (0..31)

  // B fragments: persistent in registers across all steps (96 VGPR)
  f16x8 bfr[3][8];
  #pragma unroll
  for (int s = 0; s < 3; ++s)
    #pragma unroll
    for (int ks = 0; ks < 8; ++ks)
      bfr[s][ks] = *reinterpret_cast<const f16x8*>(
          &Whh[(size_t)(s * kH + j0 + ln) * kH + kw + ks * 32 + khi * 8]);

  // own-column h in f32 registers; biases preloaded
  float hreg[2][2];
  float bR[2], bZ[2], bN[2];
  #pragma unroll
  for (int e = 0; e < 2; ++e) {
    const int j = j0 + 2 * q + e;
    hreg[0][e] = lh[(size_t)mB * kH + j];
    hreg[1][e] = lh[(size_t)(mB + 32) * kH + j];
    bR[e] = bhh[j];
    bZ[e] = bhh[kH + j];
    bN[e] = bhh[2 * kH + j];
  }

  for (int step = 0; step < kN; ++step) {
    const f16* hh  = (step & 1) ? HHb : HHa;
    f16*       hho = (step & 1) ? HHa : HHb;

    // gi prefetch for this step (no h dependence; hides under af+MFMA)
    float2 giL[2][3];
    #pragma unroll
    for (int hm = 0; hm < 2; ++hm) {
      const size_t mm = (size_t)step * kB + mB + hm * 32;
      #pragma unroll
      for (int s = 0; s < 3; ++s)
        giL[hm][s] = *reinterpret_cast<const float2*>(&gi[mm * k3H + s * kH + j0 + 2 * q]);
    }

    // A fragments: direct global->reg, all 32 loads in flight at once
    f16x8 af[8][4];
    #pragma unroll
    for (int ks = 0; ks < 8; ++ks)
      #pragma unroll
      for (int mi = 0; mi < 4; ++mi)
        af[ks][mi] = *reinterpret_cast<const f16x8*>(
            &hh[(size_t)(mi * 16 + ln) * kH + kw + ks * 32 + khi * 8]);

    f32x4v acc[4][3] = {};
    #pragma unroll
    for (int ks = 0; ks < 8; ++ks)
      #pragma unroll
      for (int mi = 0; mi < 4; ++mi)
        #pragma unroll
        for (int s = 0; s < 3; ++s)
          acc[mi][s] = __builtin_amdgcn_mfma_f32_16x16x32_f16(af[ks][mi], bfr[s][ks], acc[mi][s], 0, 0, 0);

    // K-split partials -> LDS (padded pitch 49: conflict-free)
    #pragma unroll
    for (int mi = 0; mi < 4; ++mi)
      #pragma unroll
      for (int s = 0; s < 3; ++s)
        #pragma unroll
        for (int r = 0; r < 4; ++r)
          ghp[wave][mi * 16 + khi * 4 + r][s * 16 + ln] = acc[mi][s][r];
    __syncthreads();

    // gate fusion: each thread owns rows {mB, mB+32} x cols {2q, 2q+1}
    #pragma unroll
    for (int hm = 0; hm < 2; ++hm) {
      const int m = mB + hm * 32;
      const size_t mm = (size_t)step * kB + m;
      float hv[2];
      #pragma unroll
      for (int e = 0; e < 2; ++e) {
        const int jj = 2 * q + e;
        const float gr = ghp[0][m][jj]      + ghp[1][m][jj]      + ghp[2][m][jj]      + ghp[3][m][jj]      + bR[e];
        const float gz = ghp[0][m][16 + jj] + ghp[1][m][16 + jj] + ghp[2][m][16 + jj] + ghp[3][m][16 + jj] + bZ[e];
        const float gn = ghp[0][m][32 + jj] + ghp[1][m][32 + jj] + ghp[2][m][32 + jj] + ghp[3][m][32 + jj] + bN[e];
        const float ir  = (e ? giL[hm][0].y : giL[hm][0].x);
        const float iz  = (e ? giL[hm][1].y : giL[hm][1].x);
        const float inn = (e ? giL[hm][2].y : giL[hm][2].x);
        const float r  = 1.0f / (1.0f + expf(-(ir + gr)));
        const float z  = 1.0f / (1.0f + expf(-(iz + gz)));
        const float nn = tanhf(inn + r * gn);
        hv[e] = (1.0f - z) * nn + z * hreg[hm][e];
        hreg[hm][e] = hv[e];
      }
      const uint32_t pk = pack_f16x2((f16)hv[0], (f16)hv[1]);
      // cross-block exchange: write-through to coherence point (sc1), no wbl2
      __hip_atomic_store((uint32_t*)&hho[(size_t)m * kH + j0 + 2 * q], pk,
                         __ATOMIC_RELAXED, __HIP_MEMORY_SCOPE_AGENT);
      *reinterpret_cast<uint32_t*>(&cath[mm * (size_t)k3H + j0 + 2 * q]) = pk;
      if (step == kN - 1) {
        float2 hv2 = { hv[0], hv[1] };
        *reinterpret_cast<float2*>(&hiddenOut[(size_t)m * kH + j0 + 2 * q]) = hv2;
      }
    }
    // syncthreads drains each thread's vmcnt -> all stores at coherence point
    __syncthreads();

    if (step < kN - 1) {
      if (tid == 0) {
        __hip_atomic_fetch_add(&ctr[step], 1u, __ATOMIC_RELAXED, __HIP_MEMORY_SCOPE_AGENT);
        while (__hip_atomic_load(&ctr[step], __ATOMIC_ACQUIRE, __HIP_MEMORY_SCOPE_AGENT) < 64u)
          __builtin_amdgcn_s_sleep(4);
      }
      __syncthreads();
    }
  }
}

// ---------------- attention (softmax over t is independent of n) ----------------

__global__ void attn_prep_kernel(const float* __restrict__ attn_W, const float* __restrict__ attn_b,
                                 const float* __restrict__ v, float* __restrict__ u2,
                                 float* __restrict__ biasS) {
  const int h = blockIdx.x;        // 0..1023 -> u2[h]; 1024 -> bias scalar
  const int lane = threadIdx.x;    // 64
  float sum = 0.0f;
  if (h < kH) {
    for (int k = lane; k < kH; k += 64)
      sum += attn_W[(size_t)k * (2 * kH) + kH + h] * v[k];
  } else {
    for (int k = lane; k < kH; k += 64)
      sum += attn_b[k] * v[k];
  }
  #pragma unroll
  for (int o = 32; o > 0; o >>= 1) sum += __shfl_xor(sum, o);
  if (lane == 0) {
    if (h < kH) u2[h] = sum; else biasS[0] = sum;
  }
}

__global__ void attn_scores_kernel(const float* __restrict__ enc0, const float* __restrict__ enc1,
                                   const float* __restrict__ u2, const float* __restrict__ biasS,
                                   float* __restrict__ c) {
  const int wid  = blockIdx.x * 4 + (threadIdx.x >> 6);  // one wave per (e,t,b)
  const int lane = threadIdx.x & 63;
  const int e   = wid / (kT * kB);
  const int rem = wid % (kT * kB);
  const int t = rem / kB;
  const int b = rem % kB;
  const float* row = (e ? enc1 : enc0) + ((size_t)t * kB + b) * kH;
  float sum = 0.0f;
  #pragma unroll
  for (int i = 0; i < 4; ++i) {
    float4 ev = *reinterpret_cast<const float4*>(&row[i * 256 + lane * 4]);
    float4 uv = *reinterpret_cast<const float4*>(&u2[i * 256 + lane * 4]);
    sum += ev.x * uv.x + ev.y * uv.y + ev.z * uv.z + ev.w * uv.w;
  }
  #pragma unroll
  for (int o = 32; o > 0; o >>= 1) sum += __shfl_xor(sum, o);
  if (lane == 0) c[((size_t)e * kB + b) * kT + t] = sum + biasS[0];
}

__global__ void attn_softmax_kernel(const float* __restrict__ c, float* __restrict__ wsm,
                                    float* __restrict__ uw, float* __restrict__ bw) {
  const int eb = blockIdx.x;       // 0..127
  const int e = eb >> 6, b = eb & 63;
  __shared__ float row[kT];
  __shared__ float red[8];
  const float* cr = c + (size_t)eb * kT;
  const int tid = threadIdx.x;     // 256
  float lmax = -1e30f;
  for (int t = tid; t < kT; t += 256) { float v = cr[t]; row[t] = v; lmax = fmaxf(lmax, v); }
  #pragma unroll
  for (int o = 32; o > 0; o >>= 1) lmax = fmaxf(lmax, __shfl_xor(lmax, o));
  if ((tid & 63) == 0) red[tid >> 6] = lmax;
  __syncthreads();
  const float m = fmaxf(fmaxf(red[0], red[1]), fmaxf(red[2], red[3]));
  float lsum = 0.0f;
  for (int t = tid; t < kT; t += 256) { float ev = expf(row[t] - m); row[t] = ev; lsum += ev; }
  #pragma unroll
  for (int o = 32; o > 0; o >>= 1) lsum += __shfl_xor(lsum, o);
  if ((tid & 63) == 0) red[4 + (tid >> 6)] = lsum;
  __syncthreads();
  const float inv = 1.0f / (red[4] + red[5] + red[6] + red[7]);
  for (int t = tid; t < kT; t += 256) row[t] *= inv;
  __syncthreads();
  float* wrow = wsm + (size_t)eb * kT;
  for (int t = tid; t < kT; t += 256) wrow[t] = row[t];
  float* outp = (e ? bw : uw) + (size_t)b * kN * kT;   // w is identical for every n
  for (int i = tid; i < kN * kT; i += 256) outp[i] = row[i % kT];
}

__global__ void attn_ctx_kernel(const float* __restrict__ enc0, const float* __restrict__ enc1,
                                const float* __restrict__ wsm, f16* __restrict__ cath) {
  const int bid = blockIdx.x;          // e(2) x b(64) x hc(4)
  const int hc = bid & 3;
  const int b  = (bid >> 2) & 63;
  const int e  = bid >> 8;
  const float* enc = e ? enc1 : enc0;
  __shared__ float w[kT];
  const int tid = threadIdx.x;         // 256
  const float* wrow = wsm + ((size_t)e * kB + b) * kT;
  for (int t = tid; t < kT; t += 256) w[t] = wrow[t];
  __syncthreads();
  const int hcol = hc * 256 + tid;
  float acc = 0.0f;
  #pragma unroll 4
  for (int t = 0; t < kT; ++t)
    acc += w[t] * enc[((size_t)t * kB + b) * kH + hcol];
  const f16 v = (f16)acc;
  #pragma unroll
  for (int n = 0; n < kN; ++n)         // ctx is independent of n -> replicate
    cath[((size_t)(n * kB + b)) * k3H + kH + e * kH + hcol] = v;
}

}  // namespace

// ---------------- launch ----------------

extern "C" void kernel_launch(void* const* d_in, const int* in_sizes, int n_in,
                              void* d_out, int out_size, void* d_ws, size_t ws_size,
                              hipStream_t stream) {
  (void)in_sizes; (void)n_in; (void)out_size; (void)ws_size;
  const int*   seq    = (const int*)d_in[0];
  const float* lh     = (const float*)d_in[1];
  const float* enc0   = (const float*)d_in[2];
  const float* enc1   = (const float*)d_in[3];
  const float* emb    = (const float*)d_in[4];
  const float* W_ih   = (const float*)d_in[5];
  const float* W_hh   = (const float*)d_in[6];
  const float* b_ih   = (const float*)d_in[7];
  const float* b_hh   = (const float*)d_in[8];
  const float* attn_W = (const float*)d_in[9];
  const float* attn_b = (const float*)d_in[10];
  const float* attn_v = (const float*)d_in[11];
  const float* cW     = (const float*)d_in[12];
  const float* cb     = (const float*)d_in[13];
  const float* oW     = (const float*)d_in[14];
  const float* ob     = (const float*)d_in[15];
  float* out = (float*)d_out;

  // workspace layout (all 256B-aligned by construction)
  char* ws = (char*)d_ws;
  constexpr size_t oWih = 0;                         // 3072x1024 f16
  constexpr size_t oWhh = oWih + 6291456;
  constexpr size_t oCW  = oWhh + 6291456;
  constexpr size_t oOW  = oCW + 6291456;             // 32000x1024 f16
  constexpr size_t oX   = oOW + 65536000;            // 2048x1024 f16
  constexpr size_t oGI  = oX + 4194304;              // 2048x3072 f32
  constexpr size_t oH0  = oGI + 25165824;            // (unused, kept for layout stability)
  constexpr size_t oH1  = oH0 + 262144;
  constexpr size_t oHH0 = oH1 + 262144;              // 64x1024 f16
  constexpr size_t oHH1 = oHH0 + 131072;
  constexpr size_t oCAT = oHH1 + 131072;             // 2048x3072 f16
  constexpr size_t oH2  = oCAT + 12582912;           // 2048x1024 f16
  constexpr size_t oU2  = oH2 + 4194304;             // 1024 f32
  constexpr size_t oBS  = oU2 + 4096;                // 1 f32
  constexpr size_t oC   = oBS + 256;                 // 2x64x400 f32
  constexpr size_t oWSM = oC + 204800;               // 2x64x400 f32
  constexpr size_t oCTR = oWSM + 204800;             // 64 u32 barrier counters

  f16*   Wih_h = (f16*)(ws + oWih);
  f16*   Whh_h = (f16*)(ws + oWhh);
  f16*   cW_h  = (f16*)(ws + oCW);
  f16*   oW_h  = (f16*)(ws + oOW);
  f16*   X_h   = (f16*)(ws + oX);
  float* GI    = (float*)(ws + oGI);
  f16*   HH0   = (f16*)(ws + oHH0);
  f16*   HH1   = (f16*)(ws + oHH1);
  f16*   CAT   = (f16*)(ws + oCAT);
  f16*   H2    = (f16*)(ws + oH2);
  float* U2    = (float*)(ws + oU2);
  float* BS    = (float*)(ws + oBS);
  float* Cb    = (float*)(ws + oC);
  float* WSM   = (float*)(ws + oWSM);
  unsigned int* CTR = (unsigned int*)(ws + oCTR);

  constexpr size_t oHidden = (size_t)kM * kV;        // 65,536,000
  constexpr size_t oUW = oHidden + (size_t)kB * kH;  // 65,601,536
  constexpr size_t oBW = oUW + (size_t)kB * kN * kT; // 66,420,736

  // weight converts f32 -> f16
  cvt_f16_kernel<<<1024, 256, 0, stream>>>(W_ih, Wih_h, k3H * kH / 4);
  cvt_f16_kernel<<<1024, 256, 0, stream>>>(W_hh, Whh_h, k3H * kH / 4);
  cvt_f16_kernel<<<1024, 256, 0, stream>>>(cW,   cW_h,  kH * k3H / 4);
  cvt_f16_kernel<<<2048, 256, 0, stream>>>(oW,   oW_h,  kV * kH / 4);
  gather_x_kernel<<<kM, 256, 0, stream>>>(seq, emb, X_h);
  init_h_kernel<<<64, 256, 0, stream>>>(lh, HH0);
  hipMemsetAsync(CTR, 0, 64 * sizeof(unsigned int), stream);

  // gi = x @ W_ih^T + b_ih  (batched over all steps)
  gemm_bt_kernel<false, float><<<dim3(16, 24), 256, 0, stream>>>(X_h, Wih_h, b_ih, GI, kM, k3H, kH);

  // GRU recurrence: one persistent kernel, cheap write-through barrier per step
  gru_persist_kernel<<<64, 256, 0, stream>>>(Whh_h, b_hh, GI, lh, HH0, HH1, CAT,
                                             out + oHidden, CTR);

  // attention (n-independent): scores -> softmax (writes uw/bw replicated) -> ctx
  attn_prep_kernel<<<1025, 64, 0, stream>>>(attn_W, attn_b, attn_v, U2, BS);
  attn_scores_kernel<<<2 * kT * kB / 4, 256, 0, stream>>>(enc0, enc1, U2, BS, Cb);
  attn_softmax_kernel<<<128, 256, 0, stream>>>(Cb, WSM, out + oUW, out + oBW);
  attn_ctx_kernel<<<512, 256, 0, stream>>>(enc0, enc1, WSM, CAT);

  // h = tanh(cat @ concat_W^T + concat_b)   (f16 out for final GEMM)
  gemm_bt_kernel<true, f16><<<dim3(16, 8), 256, 0, stream>>>(CAT, cW_h, cb, H2, kM, kH, k3H);
  // output = h @ out_W^T + out_b
  gemm_bt_kernel<false, float><<<dim3(16, 250), 256, 0, stream>>>(H2, oW_h, ob, out, kM, kV, kH);
}